// Round 4
// baseline (7308.498 us; speedup 1.0000x reference)
//
#include <hip/hip_runtime.h>
#include <math.h>

typedef unsigned short u16;
typedef __attribute__((ext_vector_type(8))) short s8v;   // 8 x bf16 (4 VGPRs)
typedef __attribute__((ext_vector_type(4))) float f4v;   // MFMA accumulator
typedef __attribute__((ext_vector_type(4))) int   i4v;   // asm load payload

constexpr int kB    = 256;
constexpr int kT    = 512;
constexpr int kDIN  = 64;
constexpr int kH    = 512;
constexpr int kG3   = 1536;
constexpr int kNOUT = 128;
constexpr int kPlane = 8 * 2 * 16 * 512;   // u16 per h A-frag plane (131072)
constexpr int kXStep = 16 * 2 * 512;       // u16 per x A-frag step (16384)

#define MFMA16 __builtin_amdgcn_mfma_f32_16x16x32_bf16

__device__ __forceinline__ u16 f2bf(float f) {   // round-to-nearest-even
  union { float f; unsigned u; } v; v.f = f;
  unsigned r = (v.u + 0x7FFFu + ((v.u >> 16) & 1u)) >> 16;
  return (u16)r;
}
__device__ __forceinline__ float fsig(float x) {
  x = fminf(fmaxf(x, -30.f), 30.f);
  float e = __expf(-x);
  return __fdividef(1.f, 1.f + e);
}
__device__ __forceinline__ float ftanh(float x) {
  x = fminf(fmaxf(x, -15.f), 15.f);
  float e = __expf(-2.f * x);
  return __fdividef(1.f - e, 1.f + e);
}

// 16 A-fragment loads (16 B/lane, kt stride 1024 B), LLC-coherent bypass,
// vmcnt(0) at end — the verified round-0 consumer load.
__device__ __forceinline__ void load_afrag16(const u16* base, i4v a[16]) {
  asm volatile(
      "global_load_dwordx4 %0, %16, off sc0 sc1\n\t"
      "global_load_dwordx4 %1, %16, off offset:1024 sc0 sc1\n\t"
      "global_load_dwordx4 %2, %16, off offset:2048 sc0 sc1\n\t"
      "global_load_dwordx4 %3, %16, off offset:3072 sc0 sc1\n\t"
      "global_load_dwordx4 %4, %17, off sc0 sc1\n\t"
      "global_load_dwordx4 %5, %17, off offset:1024 sc0 sc1\n\t"
      "global_load_dwordx4 %6, %17, off offset:2048 sc0 sc1\n\t"
      "global_load_dwordx4 %7, %17, off offset:3072 sc0 sc1\n\t"
      "global_load_dwordx4 %8, %18, off sc0 sc1\n\t"
      "global_load_dwordx4 %9, %18, off offset:1024 sc0 sc1\n\t"
      "global_load_dwordx4 %10, %18, off offset:2048 sc0 sc1\n\t"
      "global_load_dwordx4 %11, %18, off offset:3072 sc0 sc1\n\t"
      "global_load_dwordx4 %12, %19, off sc0 sc1\n\t"
      "global_load_dwordx4 %13, %19, off offset:1024 sc0 sc1\n\t"
      "global_load_dwordx4 %14, %19, off offset:2048 sc0 sc1\n\t"
      "global_load_dwordx4 %15, %19, off offset:3072 sc0 sc1\n\t"
      "s_waitcnt vmcnt(0)"
      : "=&v"(a[0]), "=&v"(a[1]), "=&v"(a[2]), "=&v"(a[3]),
        "=&v"(a[4]), "=&v"(a[5]), "=&v"(a[6]), "=&v"(a[7]),
        "=&v"(a[8]), "=&v"(a[9]), "=&v"(a[10]), "=&v"(a[11]),
        "=&v"(a[12]), "=&v"(a[13]), "=&v"(a[14]), "=&v"(a[15])
      : "v"(base), "v"(base + 4 * 512), "v"(base + 8 * 512), "v"(base + 12 * 512)
      : "memory");
}
// Same 16 loads, NO trailing wait (first half of layer-1's paired load).
__device__ __forceinline__ void load16_nw(const u16* base, i4v a[16]) {
  asm volatile(
      "global_load_dwordx4 %0, %16, off sc0 sc1\n\t"
      "global_load_dwordx4 %1, %16, off offset:1024 sc0 sc1\n\t"
      "global_load_dwordx4 %2, %16, off offset:2048 sc0 sc1\n\t"
      "global_load_dwordx4 %3, %16, off offset:3072 sc0 sc1\n\t"
      "global_load_dwordx4 %4, %17, off sc0 sc1\n\t"
      "global_load_dwordx4 %5, %17, off offset:1024 sc0 sc1\n\t"
      "global_load_dwordx4 %6, %17, off offset:2048 sc0 sc1\n\t"
      "global_load_dwordx4 %7, %17, off offset:3072 sc0 sc1\n\t"
      "global_load_dwordx4 %8, %18, off sc0 sc1\n\t"
      "global_load_dwordx4 %9, %18, off offset:1024 sc0 sc1\n\t"
      "global_load_dwordx4 %10, %18, off offset:2048 sc0 sc1\n\t"
      "global_load_dwordx4 %11, %18, off offset:3072 sc0 sc1\n\t"
      "global_load_dwordx4 %12, %19, off sc0 sc1\n\t"
      "global_load_dwordx4 %13, %19, off offset:1024 sc0 sc1\n\t"
      "global_load_dwordx4 %14, %19, off offset:2048 sc0 sc1\n\t"
      "global_load_dwordx4 %15, %19, off offset:3072 sc0 sc1"
      : "=&v"(a[0]), "=&v"(a[1]), "=&v"(a[2]), "=&v"(a[3]),
        "=&v"(a[4]), "=&v"(a[5]), "=&v"(a[6]), "=&v"(a[7]),
        "=&v"(a[8]), "=&v"(a[9]), "=&v"(a[10]), "=&v"(a[11]),
        "=&v"(a[12]), "=&v"(a[13]), "=&v"(a[14]), "=&v"(a[15])
      : "v"(base), "v"(base + 4 * 512), "v"(base + 8 * 512), "v"(base + 12 * 512)
      : "memory");
}
// 16 loads + vmcnt(16): issued AFTER load16_nw, so after this wait the 16
// oldest (the nw set + any earlier stragglers) are complete; the newest 16
// (this set) may still be in flight. vmcnt retires oldest-first.
__device__ __forceinline__ void load16_w16(const u16* base, i4v a[16]) {
  asm volatile(
      "global_load_dwordx4 %0, %16, off sc0 sc1\n\t"
      "global_load_dwordx4 %1, %16, off offset:1024 sc0 sc1\n\t"
      "global_load_dwordx4 %2, %16, off offset:2048 sc0 sc1\n\t"
      "global_load_dwordx4 %3, %16, off offset:3072 sc0 sc1\n\t"
      "global_load_dwordx4 %4, %17, off sc0 sc1\n\t"
      "global_load_dwordx4 %5, %17, off offset:1024 sc0 sc1\n\t"
      "global_load_dwordx4 %6, %17, off offset:2048 sc0 sc1\n\t"
      "global_load_dwordx4 %7, %17, off offset:3072 sc0 sc1\n\t"
      "global_load_dwordx4 %8, %18, off sc0 sc1\n\t"
      "global_load_dwordx4 %9, %18, off offset:1024 sc0 sc1\n\t"
      "global_load_dwordx4 %10, %18, off offset:2048 sc0 sc1\n\t"
      "global_load_dwordx4 %11, %18, off offset:3072 sc0 sc1\n\t"
      "global_load_dwordx4 %12, %19, off sc0 sc1\n\t"
      "global_load_dwordx4 %13, %19, off offset:1024 sc0 sc1\n\t"
      "global_load_dwordx4 %14, %19, off offset:2048 sc0 sc1\n\t"
      "global_load_dwordx4 %15, %19, off offset:3072 sc0 sc1\n\t"
      "s_waitcnt vmcnt(16)"
      : "=&v"(a[0]), "=&v"(a[1]), "=&v"(a[2]), "=&v"(a[3]),
        "=&v"(a[4]), "=&v"(a[5]), "=&v"(a[6]), "=&v"(a[7]),
        "=&v"(a[8]), "=&v"(a[9]), "=&v"(a[10]), "=&v"(a[11]),
        "=&v"(a[12]), "=&v"(a[13]), "=&v"(a[14]), "=&v"(a[15])
      : "v"(base), "v"(base + 4 * 512), "v"(base + 8 * 512), "v"(base + 12 * 512)
      : "memory");
}

// 4 coherent publish stores + full drain (verified round-0).
__device__ __forceinline__ void store_h4(
    u16* p0, u16* p1, u16* p2, u16* p3,
    unsigned v0, unsigned v1, unsigned v2, unsigned v3) {
  asm volatile(
      "global_store_short %0, %4, off sc0 sc1\n\t"
      "global_store_short %1, %5, off sc0 sc1\n\t"
      "global_store_short %2, %6, off sc0 sc1\n\t"
      "global_store_short %3, %7, off sc0 sc1\n\t"
      "s_waitcnt vmcnt(0)"
      :: "v"(p0), "v"(p1), "v"(p2), "v"(p3),
         "v"(v0), "v"(v1), "v"(v2), "v"(v3)
      : "memory");
}

__device__ __forceinline__ void wait_ge(unsigned* p, unsigned tgt) {
  int guard = 0;
  while (__hip_atomic_load(p, __ATOMIC_RELAXED, __HIP_MEMORY_SCOPE_AGENT) < tgt
         && ++guard < (1 << 22))
    __builtin_amdgcn_s_sleep(1);
}

// ---------------------------------------------------------------------------
// B-frag slab for [1536][512] fp32 weights (w_hh0, w_hh1, w_ih1).
// Layout: [jt 16][f 96][lane 64][8], f = (g*2+u)*16 + kt.
// elem: row = g*512 + jt*32 + u*16 + (lane&15), k = kt*32 + (lane>>4)*8 + i
// ---------------------------------------------------------------------------
__global__ void build_wslab(const float* __restrict__ w, u16* __restrict__ d) {
  int idx  = blockIdx.x * 256 + threadIdx.x;   // 0..98303
  int lane = idx & 63, fg = idx >> 6;          // fg = jt*96 + f
  int jt = fg / 96, f = fg % 96;
  int nt = f >> 4, kt = f & 15;
  int g = nt >> 1, u = nt & 1;
  int row = g * 512 + jt * 32 + u * 16 + (lane & 15);
  int k0  = kt * 32 + (lane >> 4) * 8;
  const float* src = w + (size_t)row * 512 + k0;
  u16* dst = d + ((size_t)fg) * 512 + lane * 8;
#pragma unroll
  for (int i = 0; i < 8; i++) dst[i] = f2bf(src[i]);
}

// B-frag slab for w_ih0 [1536][64]: [jt 16][f 12][lane 64][8], f = (g*2+u)*2+kt.
__global__ void build_wslab_ih0(const float* __restrict__ w, u16* __restrict__ d) {
  int idx  = blockIdx.x * 256 + threadIdx.x;   // 0..12287
  int lane = idx & 63, fg = idx >> 6;          // fg = jt*12 + f
  int jt = fg / 12, f = fg % 12;
  int nt = f >> 1, kt = f & 1;
  int g = nt >> 1, u = nt & 1;
  int row = g * 512 + jt * 32 + u * 16 + (lane & 15);
  int k0  = kt * 32 + (lane >> 4) * 8;
  const float* src = w + (size_t)row * kDIN + k0;
  u16* dst = d + ((size_t)fg) * 512 + lane * 8;
#pragma unroll
  for (int i = 0; i < 8; i++) dst[i] = f2bf(src[i]);
}

// x [256][512][64] fp32 -> per-step A-frag planes (bf16).
// u16 at ((T*16+m)*2+kt)*512 + l*8 + i  =  x[b = m*16+(l&15)][T][k = kt*32+(l>>4)*8+i]
// (canonical A-frag mapping, derived from the verified hbuf producer/consumer pair)
__global__ void build_xplane(const float* __restrict__ x, u16* __restrict__ d) {
  int idx  = blockIdx.x * 256 + threadIdx.x;   // 0..1048575
  int lane = idx & 63, fg = idx >> 6;          // fg = (T*16+m)*2+kt
  int kt = fg & 1, m = (fg >> 1) & 15, T = fg >> 5;
  int b  = m * 16 + (lane & 15);
  int k0 = kt * 32 + (lane >> 4) * 8;
  const float* src = x + ((size_t)b * kT + T) * kDIN + k0;
  u16* dst = d + ((size_t)fg) * 512 + lane * 8;
#pragma unroll
  for (int i = 0; i < 8; i++) dst[i] = f2bf(src[i]);
}

// ---------------------------------------------------------------------------
// SINGLE persistent dispatch: both layers, all 512 steps, projections fused.
// Grid 256 blocks (1/CU), 256 threads. Blocks 0..127 layer0, 128..255 layer1.
// Group (layer, bt): bt = lb>>4, jt = lb&15 (the verified round-0 grouping).
//
// Slot schedule: slot s runs layer0 step s and layer1 step s-1 concurrently.
// Waits (tid0 / tid64 poll in parallel, then __syncthreads):
//   L0 step t:  barL0 >= 16t        (own peers' h1_{t-1} published)
//               barL1 >= 16(t-1)    (t>=2: plane being overwritten was
//                                    consumed by layer1 at its step t-2)
//   L1 step t:  barL0 >= 16(t+1)    (h1_t published)
//               barL1 >= 16t        (own peers' h2_{t-1} published)
// Arrivals: relaxed agent atomic add AFTER publish stores drained (vmcnt(0))
// and block-wide __syncthreads — the verified round-0 release pattern.
//
// Layer1 fuses proj1: gates = h1_t @ w_ih1^T (streamed B-frags, L2-resident)
//                           + h2_{t-1} @ w_hh1^T (resident B-frags).
// Layer0 fuses proj0: gates = x_t @ w_ih0^T (resident, 2 k-tiles, x from
//                     pre-swizzled xplane) + h1_{t-1} @ w_hh0^T (resident).
// n-gate keeps ih/hh accumulators separate (reference: tanh(xn + r*hn)).
// ---------------------------------------------------------------------------
__global__ __launch_bounds__(256, 1)
void rec_all(unsigned* bar, const u16* __restrict__ xpl,
             const u16* __restrict__ slab0hh, const u16* __restrict__ slab0ih,
             const u16* __restrict__ slab1hh, const u16* __restrict__ slab1ih,
             const float* __restrict__ bih0, const float* __restrict__ bhh0,
             const float* __restrict__ bih1, const float* __restrict__ bhh1,
             u16* __restrict__ hbuf, float* __restrict__ carry) {
  const int bid   = blockIdx.x;
  const int layer = bid >> 7;
  const int lb    = bid & 127;
  const int jt    = lb & 15, bt = lb >> 4;
  const int tid   = threadIdx.x;
  const int wv    = tid >> 6, lane = tid & 63;
  const int mt    = wv >> 1, u = wv & 1;
  const int jl    = lane & 15;
  const int jg    = jt * 32 + u * 16 + jl;
  const int mrow  = (lane >> 4) * 4;
  const int bbase = bt * 32 + mt * 16 + mrow;

  unsigned* barL0 = bar + (size_t)bt * 64;
  unsigned* barL1 = bar + (size_t)(8 + bt) * 64;

  const size_t cons_off = ((size_t)((bt * 2 + mt) * 16)) * 512 + lane * 8;
  const size_t prod_off = ((size_t)((bt * 2 + mt) * 16 + jt)) * 512 +
                          (size_t)(16 * (u * 2 + (jl >> 3))) * 8 + (jl & 7);

  if (layer == 0) {
    // ---- resident weights: w_hh0 (48 frags) + w_ih0 (6 frags) ----
    s8v bh[3][16];
    {
      const u16* base = slab0hh + (size_t)jt * 96 * 512 + (size_t)lane * 8;
#pragma unroll
      for (int g = 0; g < 3; ++g)
#pragma unroll
        for (int kt = 0; kt < 16; ++kt)
          bh[g][kt] = *(const s8v*)(base + (size_t)((g * 2 + u) * 16 + kt) * 512);
    }
    s8v bx[3][2];
    {
      const u16* base = slab0ih + (size_t)jt * 12 * 512 + (size_t)lane * 8;
#pragma unroll
      for (int g = 0; g < 3; ++g)
#pragma unroll
        for (int kt = 0; kt < 2; ++kt)
          bx[g][kt] = *(const s8v*)(base + (size_t)((g * 2 + u) * 2 + kt) * 512);
    }
    const float br  = bih0[jg] + bhh0[jg];
    const float bz  = bih0[512 + jg] + bhh0[512 + jg];
    const float bni = bih0[1024 + jg], bnh = bhh0[1024 + jg];
    float hp[4] = {0.f, 0.f, 0.f, 0.f};

    const size_t xoff = (size_t)((bt * 2 + mt) * 2) * 512 + (size_t)lane * 8;
    s8v ax0 = *(const s8v*)(xpl + xoff);
    s8v ax1 = *(const s8v*)(xpl + xoff + 512);

    for (int t = 0; t < kT; ++t) {
      if (tid == 0) {
        if (t) wait_ge(barL0, 16u * (unsigned)t);
      } else if (tid == 64) {
        if (t >= 2) wait_ge(barL1, 16u * (unsigned)(t - 1));
      }
      __syncthreads();

      i4v a[16];
      load_afrag16(hbuf + (size_t)(t & 1) * kPlane + cons_off, a);

      const f4v z4 = {0.f, 0.f, 0.f, 0.f};
      f4v acc0, acc1, acc2, acc2x;
      acc0  = MFMA16(ax0, bx[0][0], z4, 0, 0, 0);
      acc0  = MFMA16(ax1, bx[0][1], acc0, 0, 0, 0);
      acc1  = MFMA16(ax0, bx[1][0], z4, 0, 0, 0);
      acc1  = MFMA16(ax1, bx[1][1], acc1, 0, 0, 0);
      acc2x = MFMA16(ax0, bx[2][0], z4, 0, 0, 0);
      acc2x = MFMA16(ax1, bx[2][1], acc2x, 0, 0, 0);
      acc2  = z4;
#pragma unroll
      for (int kt = 0; kt < 16; ++kt) {
        const s8v av = __builtin_bit_cast(s8v, a[kt]);
        acc0 = MFMA16(av, bh[0][kt], acc0, 0, 0, 0);
        acc1 = MFMA16(av, bh[1][kt], acc1, 0, 0, 0);
        acc2 = MFMA16(av, bh[2][kt], acc2, 0, 0, 0);
      }

      unsigned hv[4];
#pragma unroll
      for (int r = 0; r < 4; ++r) {
        float rr = fsig(acc0[r] + br);
        float zz = fsig(acc1[r] + bz);
        float nn = ftanh(acc2x[r] + bni + rr * (acc2[r] + bnh));
        float hn = (1.f - zz) * nn + zz * hp[r];
        hp[r] = hn;
        hv[r] = f2bf(hn);
      }

      u16* pb = hbuf + (size_t)((t + 1) & 1) * kPlane + prod_off;
      store_h4(pb + (size_t)(mrow + 0) * 8, pb + (size_t)(mrow + 1) * 8,
               pb + (size_t)(mrow + 2) * 8, pb + (size_t)(mrow + 3) * 8,
               hv[0], hv[1], hv[2], hv[3]);
      __syncthreads();
      if (tid == 0)
        __hip_atomic_fetch_add(barL0, 1u, __ATOMIC_RELAXED,
                               __HIP_MEMORY_SCOPE_AGENT);
      if (t + 1 < kT) {   // prefetch next x-frags (constant data, cached path)
        const u16* xb = xpl + (size_t)(t + 1) * kXStep + xoff;
        ax0 = *(const s8v*)xb;
        ax1 = *(const s8v*)(xb + 512);
      }
    }
  } else {
    // ---- resident: w_hh1 (48 frags). w_ih1 streamed from L2 each step ----
    s8v bh[3][16];
    {
      const u16* base = slab1hh + (size_t)jt * 96 * 512 + (size_t)lane * 8;
#pragma unroll
      for (int g = 0; g < 3; ++g)
#pragma unroll
        for (int kt = 0; kt < 16; ++kt)
          bh[g][kt] = *(const s8v*)(base + (size_t)((g * 2 + u) * 16 + kt) * 512);
    }
    const u16* wbase = slab1ih + (size_t)jt * 96 * 512 + (size_t)lane * 8;
    const float br  = bih1[jg] + bhh1[jg];
    const float bz  = bih1[512 + jg] + bhh1[512 + jg];
    const float bni = bih1[1024 + jg], bnh = bhh1[1024 + jg];
    float hp[4] = {0.f, 0.f, 0.f, 0.f};

    for (int t = 0; t < kT; ++t) {
      if (tid == 0) {
        wait_ge(barL0, 16u * (unsigned)(t + 1));
      } else if (tid == 64) {
        if (t) wait_ge(barL1, 16u * (unsigned)t);
      }
      __syncthreads();

      // paired loads: h1_t (a) then h2_{t-1} (a2); vmcnt(16) => a complete.
      i4v a[16], a2[16];
      load16_nw(hbuf + (size_t)((t + 1) & 1) * kPlane + cons_off, a);
      load16_w16(hbuf + (size_t)(2 + (t & 1)) * kPlane + cons_off, a2);
      __builtin_amdgcn_sched_barrier(0);   // keep ih MFMAs below the vmcnt(16)

      const f4v z4 = {0.f, 0.f, 0.f, 0.f};
      f4v acc0 = z4, acc1 = z4, acc2 = z4, acc2x = z4;
#pragma unroll 4
      for (int kt = 0; kt < 16; ++kt) {     // streamed w_ih1 (L2-resident)
        s8v b0 = *(const s8v*)(wbase + (size_t)((0 + u) * 16 + kt) * 512);
        s8v b1 = *(const s8v*)(wbase + (size_t)((2 + u) * 16 + kt) * 512);
        s8v b2 = *(const s8v*)(wbase + (size_t)((4 + u) * 16 + kt) * 512);
        const s8v av = __builtin_bit_cast(s8v, a[kt]);
        acc0  = MFMA16(av, b0, acc0, 0, 0, 0);
        acc1  = MFMA16(av, b1, acc1, 0, 0, 0);
        acc2x = MFMA16(av, b2, acc2x, 0, 0, 0);
      }
      asm volatile("s_waitcnt vmcnt(0)" ::: "memory");  // a2 (h2) ready
      __builtin_amdgcn_sched_barrier(0);   // rule #18: pin MFMAs below wait
#pragma unroll
      for (int kt = 0; kt < 16; ++kt) {
        const s8v av = __builtin_bit_cast(s8v, a2[kt]);
        acc0 = MFMA16(av, bh[0][kt], acc0, 0, 0, 0);
        acc1 = MFMA16(av, bh[1][kt], acc1, 0, 0, 0);
        acc2 = MFMA16(av, bh[2][kt], acc2, 0, 0, 0);
      }

      unsigned hv[4];
#pragma unroll
      for (int r = 0; r < 4; ++r) {
        float rr = fsig(acc0[r] + br);
        float zz = fsig(acc1[r] + bz);
        float nn = ftanh(acc2x[r] + bni + rr * (acc2[r] + bnh));
        float hn = (1.f - zz) * nn + zz * hp[r];
        hp[r] = hn;
        hv[r] = f2bf(hn);
      }

      u16* pb = hbuf + (size_t)(2 + ((t + 1) & 1)) * kPlane + prod_off;
      store_h4(pb + (size_t)(mrow + 0) * 8, pb + (size_t)(mrow + 1) * 8,
               pb + (size_t)(mrow + 2) * 8, pb + (size_t)(mrow + 3) * 8,
               hv[0], hv[1], hv[2], hv[3]);
      __syncthreads();
      if (tid == 0)
        __hip_atomic_fetch_add(barL1, 1u, __ATOMIC_RELAXED,
                               __HIP_MEMORY_SCOPE_AGENT);
    }

    // final h2 -> carry (fp32) for the FC
#pragma unroll
    for (int r = 0; r < 4; ++r)
      carry[(size_t)(bbase + r) * 512 + jg] = hp[r];
  }
}

// ---------------------------------------------------------------------------
__global__ __launch_bounds__(128)
void fc_kernel(const float* __restrict__ h, const float* __restrict__ wfc,
               const float* __restrict__ bfc, float* __restrict__ out) {
  const int b = blockIdx.x;
  const int n = threadIdx.x;
  const float* hrow = h + (size_t)b * kH;
  const float* wrow = wfc + (size_t)n * kH;
  float acc = 0.f;
#pragma unroll 4
  for (int k = 0; k < kH; k += 4) {
    const float4 hv = *(const float4*)&hrow[k];
    const float4 wv = *(const float4*)&wrow[k];
    acc = fmaf(hv.x, wv.x, acc); acc = fmaf(hv.y, wv.y, acc);
    acc = fmaf(hv.z, wv.z, acc); acc = fmaf(hv.w, wv.w, acc);
  }
  out[(size_t)b * kNOUT + n] = acc + bfc[n];
}

// ---------------------------------------------------------------------------
extern "C" void kernel_launch(void* const* d_in, const int* in_sizes, int n_in,
                              void* d_out, int out_size, void* d_ws, size_t ws_size,
                              hipStream_t stream) {
  const float* x     = (const float*)d_in[0];
  const float* w_ih0 = (const float*)d_in[1];
  const float* w_hh0 = (const float*)d_in[2];
  const float* b_ih0 = (const float*)d_in[3];
  const float* b_hh0 = (const float*)d_in[4];
  const float* w_ih1 = (const float*)d_in[5];
  const float* w_hh1 = (const float*)d_in[6];
  const float* b_ih1 = (const float*)d_in[7];
  const float* b_hh1 = (const float*)d_in[8];
  const float* w_fc  = (const float*)d_in[9];
  const float* b_fc  = (const float*)d_in[10];
  float* out = (float*)d_out;

  // workspace (~21 MB total)
  char* p = (char*)d_ws;
  auto carve = [&](size_t bytes) {
    char* r = p; p += (bytes + 255) & ~(size_t)255; return r;
  };
  u16* slab0hh = (u16*)carve((size_t)kG3 * kH * 2);     // 1.5 MB
  u16* slab1hh = (u16*)carve((size_t)kG3 * kH * 2);     // 1.5 MB
  u16* slab1ih = (u16*)carve((size_t)kG3 * kH * 2);     // 1.5 MB
  u16* slab0ih = (u16*)carve((size_t)kG3 * kDIN * 2);   // 192 KB
  u16* xpl     = (u16*)carve((size_t)kT * kXStep * 2);  // 16.8 MB
  u16* hbuf    = (u16*)carve(4 * (size_t)kPlane * 2);   // 1 MB
  float* carry = (float*)carve((size_t)kB * kH * 4);    // 512 KB
  unsigned* bar = (unsigned*)carve(16 * 64 * sizeof(unsigned));  // 4 KB

  // prologue: weight/x swizzles + zero h planes + barrier counters
  build_wslab<<<384, 256, 0, stream>>>(w_hh0, slab0hh);
  build_wslab<<<384, 256, 0, stream>>>(w_hh1, slab1hh);
  build_wslab<<<384, 256, 0, stream>>>(w_ih1, slab1ih);
  build_wslab_ih0<<<48, 256, 0, stream>>>(w_ih0, slab0ih);
  build_xplane<<<4096, 256, 0, stream>>>(x, xpl);
  hipMemsetAsync(hbuf, 0, 4 * (size_t)kPlane * 2, stream);
  hipMemsetAsync(bar, 0, 16 * 64 * sizeof(unsigned), stream);

  // the whole 2-layer recurrence, single persistent dispatch
  rec_all<<<dim3(256), dim3(256), 0, stream>>>(
      bar, xpl, slab0hh, slab0ih, slab1hh, slab1ih,
      b_ih0, b_hh0, b_ih1, b_hh1, hbuf, carry);

  // final FC on layer-1 terminal state
  fc_kernel<<<dim3(kB), dim3(kNOUT), 0, stream>>>(carry, w_fc, b_fc, out);
}

// Round 5
// 2332.946 us; speedup vs baseline: 3.1327x; 3.1327x over previous
//
#include <hip/hip_runtime.h>
#include <math.h>

typedef unsigned short u16;
typedef __attribute__((ext_vector_type(8))) short s8v;   // 8 x bf16 (4 VGPRs)
typedef __attribute__((ext_vector_type(4))) float f4v;   // MFMA accumulator
typedef __attribute__((ext_vector_type(4))) int   i4v;   // asm load payload

constexpr int kB    = 256;
constexpr int kT    = 512;
constexpr int kDIN  = 64;
constexpr int kH    = 512;
constexpr int kG3   = 1536;
constexpr int kNOUT = 128;
constexpr int kPlane = 8 * 2 * 16 * 512;   // u16 per h A-frag plane (131072)
constexpr int kXStep = 16 * 2 * 512;       // u16 per x A-frag step (16384)

#define MFMA16 __builtin_amdgcn_mfma_f32_16x16x32_bf16

__device__ __forceinline__ u16 f2bf(float f) {   // round-to-nearest-even
  union { float f; unsigned u; } v; v.f = f;
  unsigned r = (v.u + 0x7FFFu + ((v.u >> 16) & 1u)) >> 16;
  return (u16)r;
}
__device__ __forceinline__ float fsig(float x) {
  x = fminf(fmaxf(x, -30.f), 30.f);
  float e = __expf(-x);
  return __fdividef(1.f, 1.f + e);
}
__device__ __forceinline__ float ftanh(float x) {
  x = fminf(fmaxf(x, -15.f), 15.f);
  float e = __expf(-2.f * x);
  return __fdividef(1.f - e, 1.f + e);
}

// 16 A-fragment loads (16 B/lane, kt stride 1024 B), LLC-coherent bypass,
// NO trailing wait — caller places compute between issue and vmcnt(0).
__device__ __forceinline__ void load16_nw(const u16* base, i4v a[16]) {
  asm volatile(
      "global_load_dwordx4 %0, %16, off sc0 sc1\n\t"
      "global_load_dwordx4 %1, %16, off offset:1024 sc0 sc1\n\t"
      "global_load_dwordx4 %2, %16, off offset:2048 sc0 sc1\n\t"
      "global_load_dwordx4 %3, %16, off offset:3072 sc0 sc1\n\t"
      "global_load_dwordx4 %4, %17, off sc0 sc1\n\t"
      "global_load_dwordx4 %5, %17, off offset:1024 sc0 sc1\n\t"
      "global_load_dwordx4 %6, %17, off offset:2048 sc0 sc1\n\t"
      "global_load_dwordx4 %7, %17, off offset:3072 sc0 sc1\n\t"
      "global_load_dwordx4 %8, %18, off sc0 sc1\n\t"
      "global_load_dwordx4 %9, %18, off offset:1024 sc0 sc1\n\t"
      "global_load_dwordx4 %10, %18, off offset:2048 sc0 sc1\n\t"
      "global_load_dwordx4 %11, %18, off offset:3072 sc0 sc1\n\t"
      "global_load_dwordx4 %12, %19, off sc0 sc1\n\t"
      "global_load_dwordx4 %13, %19, off offset:1024 sc0 sc1\n\t"
      "global_load_dwordx4 %14, %19, off offset:2048 sc0 sc1\n\t"
      "global_load_dwordx4 %15, %19, off offset:3072 sc0 sc1"
      : "=&v"(a[0]), "=&v"(a[1]), "=&v"(a[2]), "=&v"(a[3]),
        "=&v"(a[4]), "=&v"(a[5]), "=&v"(a[6]), "=&v"(a[7]),
        "=&v"(a[8]), "=&v"(a[9]), "=&v"(a[10]), "=&v"(a[11]),
        "=&v"(a[12]), "=&v"(a[13]), "=&v"(a[14]), "=&v"(a[15])
      : "v"(base), "v"(base + 4 * 512), "v"(base + 8 * 512), "v"(base + 12 * 512)
      : "memory");
}

// Layer-0 publish: 4 coherent hbuf stores FIRST, then 4 plain h1pl stores,
// then vmcnt(4) — waits only the hbuf 4; h1pl drains during the barrier
// round (vmcnt retires in issue order). (Verified round-0 pattern.)
__device__ __forceinline__ void store_h_l0(
    u16* p0, u16* p1, u16* p2, u16* p3,
    u16* q0, u16* q1, u16* q2, u16* q3,
    unsigned v0, unsigned v1, unsigned v2, unsigned v3) {
  asm volatile(
      "global_store_short %0, %8, off sc0 sc1\n\t"
      "global_store_short %1, %9, off sc0 sc1\n\t"
      "global_store_short %2, %10, off sc0 sc1\n\t"
      "global_store_short %3, %11, off sc0 sc1\n\t"
      "global_store_short %4, %8, off\n\t"
      "global_store_short %5, %9, off\n\t"
      "global_store_short %6, %10, off\n\t"
      "global_store_short %7, %11, off\n\t"
      "s_waitcnt vmcnt(4)"
      :: "v"(p0), "v"(p1), "v"(p2), "v"(p3),
         "v"(q0), "v"(q1), "v"(q2), "v"(q3),
         "v"(v0), "v"(v1), "v"(v2), "v"(v3)
      : "memory");
}
// Layer-1: 4 coherent stores + full drain. (Verified round-0.)
__device__ __forceinline__ void store_h_l1(
    u16* p0, u16* p1, u16* p2, u16* p3,
    unsigned v0, unsigned v1, unsigned v2, unsigned v3) {
  asm volatile(
      "global_store_short %0, %4, off sc0 sc1\n\t"
      "global_store_short %1, %5, off sc0 sc1\n\t"
      "global_store_short %2, %6, off sc0 sc1\n\t"
      "global_store_short %3, %7, off sc0 sc1\n\t"
      "s_waitcnt vmcnt(0)"
      :: "v"(p0), "v"(p1), "v"(p2), "v"(p3),
         "v"(v0), "v"(v1), "v"(v2), "v"(v3)
      : "memory");
}

// ---------------------------------------------------------------------------
// B-frag slab for [1536][512] fp32 weights (w_hh0, w_hh1, w_ih1).
// Layout: [jt 16][f 96][lane 64][8], f = (g*2+u)*16 + kt.   (Verified r0/r4.)
// ---------------------------------------------------------------------------
__global__ void build_wslab(const float* __restrict__ w, u16* __restrict__ d) {
  int idx  = blockIdx.x * 256 + threadIdx.x;   // 0..98303
  int lane = idx & 63, fg = idx >> 6;          // fg = jt*96 + f
  int jt = fg / 96, f = fg % 96;
  int nt = f >> 4, kt = f & 15;
  int g = nt >> 1, u = nt & 1;
  int row = g * 512 + jt * 32 + u * 16 + (lane & 15);
  int k0  = kt * 32 + (lane >> 4) * 8;
  const float* src = w + (size_t)row * 512 + k0;
  u16* dst = d + ((size_t)fg) * 512 + lane * 8;
#pragma unroll
  for (int i = 0; i < 8; i++) dst[i] = f2bf(src[i]);
}

// B-frag slab for w_ih0 [1536][64]: [jt 16][f 12][lane 64][8], f=(g*2+u)*2+kt.
// (Verified round-4.)
__global__ void build_wslab_ih0(const float* __restrict__ w, u16* __restrict__ d) {
  int idx  = blockIdx.x * 256 + threadIdx.x;   // 0..12287
  int lane = idx & 63, fg = idx >> 6;          // fg = jt*12 + f
  int jt = fg / 12, f = fg % 12;
  int nt = f >> 1, kt = f & 1;
  int g = nt >> 1, u = nt & 1;
  int row = g * 512 + jt * 32 + u * 16 + (lane & 15);
  int k0  = kt * 32 + (lane >> 4) * 8;
  const float* src = w + (size_t)row * kDIN + k0;
  u16* dst = d + ((size_t)fg) * 512 + lane * 8;
#pragma unroll
  for (int i = 0; i < 8; i++) dst[i] = f2bf(src[i]);
}

// x [256][512][64] fp32 -> per-step A-frag planes (bf16). (Verified round-4.)
__global__ void build_xplane(const float* __restrict__ x, u16* __restrict__ d) {
  int idx  = blockIdx.x * 256 + threadIdx.x;   // 0..1048575
  int lane = idx & 63, fg = idx >> 6;          // fg = (T*16+m)*2+kt
  int kt = fg & 1, m = (fg >> 1) & 15, T = fg >> 5;
  int b  = m * 16 + (lane & 15);
  int k0 = kt * 32 + (lane >> 4) * 8;
  const float* src = x + ((size_t)b * kT + T) * kDIN + k0;
  u16* dst = d + ((size_t)fg) * 512 + lane * 8;
#pragma unroll
  for (int i = 0; i < 8; i++) dst[i] = f2bf(src[i]);
}

// ---------------------------------------------------------------------------
// Chunk-decoupled fused recurrence. Grid 256 blocks (1/CU), 256 threads.
// Blocks 0..127: layer0 chunk c (fused proj0 via xplane). Blocks 128..255:
// layer1 chunk c-1 (fused proj1: h1pl A-frags + w_ih1 from LDS).
// Barrier protocol is byte-identical to the verified round-0 kernel:
// per-(layer,bt) 16-block groups, tid0 LLC poll -> __syncthreads ->
// coherent loads/stores -> drain -> __syncthreads -> relaxed agent arrive.
// Layer1's h1 input (h1pl, chunk c-1) is STABLE data written in the
// previous dispatch -> zero step-level cross-layer coupling (round-4's
// mistake avoided). Its per-step ih work (16 frag prefetch + 48 LDS-fed
// MFMAs) hides in the barrier-wait + h2-load shadow.
// ---------------------------------------------------------------------------
__global__ __launch_bounds__(256, 1)
void rec_fused(int c, int TC, int nc, unsigned bar_base16, unsigned* bar,
               const u16* __restrict__ xpl,
               const u16* __restrict__ slab0hh, const u16* __restrict__ slab0ih,
               const u16* __restrict__ slab1hh, const u16* __restrict__ slab1ih,
               const float* __restrict__ bih0, const float* __restrict__ bhh0,
               const float* __restrict__ bih1, const float* __restrict__ bhh1,
               u16* __restrict__ h1pl, u16* __restrict__ hbuf,
               float* __restrict__ carry) {
  __shared__ u16 ldsw[96 * 512];   // layer1: w_ih1 jt-slice (96 KB)

  const int bid   = blockIdx.x;
  const int layer = bid >> 7;
  const int lb    = bid & 127;
  const int jt    = lb & 15, bt = lb >> 4;
  const int cc    = (layer == 0) ? c : c - 1;
  const bool active = (cc >= 0 && cc < nc);

  unsigned* mybar = bar + (size_t)(layer * 8 + bt) * 64;   // own cacheline

  if (!active) {   // whole (layer,bt) group inactive together: fast-forward
    if (threadIdx.x == 0)
      __hip_atomic_fetch_add(mybar, (unsigned)TC, __ATOMIC_RELAXED,
                             __HIP_MEMORY_SCOPE_AGENT);
    return;
  }

  const int tid   = threadIdx.x;
  const int wv    = tid >> 6, lane = tid & 63;
  const int mt    = wv >> 1, u = wv & 1;
  const int jl    = lane & 15;
  const int jg    = jt * 32 + u * 16 + jl;
  const int mrow  = (lane >> 4) * 4;
  const int bbase = bt * 32 + mt * 16 + mrow;

  const size_t cons_off = ((size_t)((bt * 2 + mt) * 16)) * 512 + lane * 8;
  const size_t prod_off = ((size_t)((bt * 2 + mt) * 16 + jt)) * 512 +
                          (size_t)(16 * (u * 2 + (jl >> 3))) * 8 + (jl & 7);
  float* mycarry = carry + (size_t)layer * kB * kH;

  if (layer == 0) {
    // ---- resident: w_hh0 (48 frags) + w_ih0 (6 frags) ----
    s8v bh[3][16];
    {
      const u16* base = slab0hh + (size_t)jt * 96 * 512 + (size_t)lane * 8;
#pragma unroll
      for (int g = 0; g < 3; ++g)
#pragma unroll
        for (int kt = 0; kt < 16; ++kt)
          bh[g][kt] = *(const s8v*)(base + (size_t)((g * 2 + u) * 16 + kt) * 512);
    }
    s8v bx[3][2];
    {
      const u16* base = slab0ih + (size_t)jt * 12 * 512 + (size_t)lane * 8;
#pragma unroll
      for (int g = 0; g < 3; ++g)
#pragma unroll
        for (int kt = 0; kt < 2; ++kt)
          bx[g][kt] = *(const s8v*)(base + (size_t)((g * 2 + u) * 2 + kt) * 512);
    }
    const float br  = bih0[jg] + bhh0[jg];
    const float bz  = bih0[512 + jg] + bhh0[512 + jg];
    const float bni = bih0[1024 + jg], bnh = bhh0[1024 + jg];

    float hp[4];
#pragma unroll
    for (int r = 0; r < 4; ++r)
      hp[r] = mycarry[(size_t)(bbase + r) * 512 + jg];

    const size_t xoff = (size_t)((bt * 2 + mt) * 2) * 512 + (size_t)lane * 8;
    const u16* xb0 = xpl + (size_t)(cc * TC) * kXStep + xoff;
    s8v ax0 = *(const s8v*)xb0;
    s8v ax1 = *(const s8v*)(xb0 + 512);

    for (int t = 0; t < TC; ++t) {
      if (tid == 0) {
        unsigned tgt = bar_base16 + 16u * (unsigned)t;
        int guard = 0;
        while (__hip_atomic_load(mybar, __ATOMIC_RELAXED,
                                 __HIP_MEMORY_SCOPE_AGENT) < tgt
               && ++guard < (1 << 21))
          __builtin_amdgcn_s_sleep(1);
      }
      __syncthreads();

      // issue h1_{t-1} loads; ih MFMAs run under the LLC latency
      i4v a[16];
      load16_nw(hbuf + (size_t)(t & 1) * kPlane + cons_off, a);

      const f4v z4 = {0.f, 0.f, 0.f, 0.f};
      f4v acc0, acc1, acc2, acc2x;
      acc0  = MFMA16(ax0, bx[0][0], z4, 0, 0, 0);
      acc0  = MFMA16(ax1, bx[0][1], acc0, 0, 0, 0);
      acc1  = MFMA16(ax0, bx[1][0], z4, 0, 0, 0);
      acc1  = MFMA16(ax1, bx[1][1], acc1, 0, 0, 0);
      acc2x = MFMA16(ax0, bx[2][0], z4, 0, 0, 0);
      acc2x = MFMA16(ax1, bx[2][1], acc2x, 0, 0, 0);
      acc2  = z4;
      asm volatile("s_waitcnt vmcnt(0)" ::: "memory");
      __builtin_amdgcn_sched_barrier(0);   // rule #18: pin hh MFMAs below
#pragma unroll
      for (int kt = 0; kt < 16; ++kt) {
        const s8v av = __builtin_bit_cast(s8v, a[kt]);
        acc0 = MFMA16(av, bh[0][kt], acc0, 0, 0, 0);
        acc1 = MFMA16(av, bh[1][kt], acc1, 0, 0, 0);
        acc2 = MFMA16(av, bh[2][kt], acc2, 0, 0, 0);
      }

      unsigned hv[4];
#pragma unroll
      for (int r = 0; r < 4; ++r) {
        float rr = fsig(acc0[r] + br);
        float zz = fsig(acc1[r] + bz);
        float nn = ftanh(acc2x[r] + bni + rr * (acc2[r] + bnh));
        float hn = (1.f - zz) * nn + zz * hp[r];
        hp[r] = hn;
        hv[r] = f2bf(hn);
      }

      // publish h1_t: hbuf (group exchange, coherent) + h1pl (next dispatch)
      u16* pb = hbuf + (size_t)((t + 1) & 1) * kPlane + prod_off;
      u16* qb = h1pl + (size_t)((cc & 1) * TC + t) * kPlane + prod_off;
      store_h_l0(pb + (size_t)(mrow + 0) * 8, pb + (size_t)(mrow + 1) * 8,
                 pb + (size_t)(mrow + 2) * 8, pb + (size_t)(mrow + 3) * 8,
                 qb + (size_t)(mrow + 0) * 8, qb + (size_t)(mrow + 1) * 8,
                 qb + (size_t)(mrow + 2) * 8, qb + (size_t)(mrow + 3) * 8,
                 hv[0], hv[1], hv[2], hv[3]);
      __syncthreads();
      if (tid == 0)
        __hip_atomic_fetch_add(mybar, 1u, __ATOMIC_RELAXED,
                               __HIP_MEMORY_SCOPE_AGENT);
      if (t + 1 < TC) {   // x frags for t+1 fly during next wait phase
        const u16* xb = xpl + (size_t)(cc * TC + t + 1) * kXStep + xoff;
        ax0 = *(const s8v*)xb;
        ax1 = *(const s8v*)(xb + 512);
      }
    }
#pragma unroll
    for (int r = 0; r < 4; ++r)
      mycarry[(size_t)(bbase + r) * 512 + jg] = hp[r];
  } else {
    // ---- w_ih1 jt-slice -> LDS (once); w_hh1 resident in VGPRs ----
    {
      const u16* src = slab1ih + (size_t)jt * 96 * 512;
      for (int i = tid; i < 96 * 512 / 8; i += 256)
        *(s8v*)&ldsw[i * 8] = *(const s8v*)&src[i * 8];
    }
    s8v bh[3][16];
    {
      const u16* base = slab1hh + (size_t)jt * 96 * 512 + (size_t)lane * 8;
#pragma unroll
      for (int g = 0; g < 3; ++g)
#pragma unroll
        for (int kt = 0; kt < 16; ++kt)
          bh[g][kt] = *(const s8v*)(base + (size_t)((g * 2 + u) * 16 + kt) * 512);
    }
    const float br  = bih1[jg] + bhh1[jg];
    const float bz  = bih1[512 + jg] + bhh1[512 + jg];
    const float bni = bih1[1024 + jg], bnh = bhh1[1024 + jg];

    float hp[4];
#pragma unroll
    for (int r = 0; r < 4; ++r)
      hp[r] = mycarry[(size_t)(bbase + r) * 512 + jg];

    // h1 A-frag source for chunk cc (stable data from previous dispatch)
    const u16* h1base = h1pl + (size_t)((cc & 1) * TC) * kPlane + cons_off;
    s8v a1[16];
#pragma unroll
    for (int kt = 0; kt < 16; ++kt)
      a1[kt] = *(const s8v*)(h1base + (size_t)kt * 512);

    for (int t = 0; t < TC; ++t) {
      if (tid == 0) {
        unsigned tgt = bar_base16 + 16u * (unsigned)t;
        int guard = 0;
        while (__hip_atomic_load(mybar, __ATOMIC_RELAXED,
                                 __HIP_MEMORY_SCOPE_AGENT) < tgt
               && ++guard < (1 << 21))
          __builtin_amdgcn_s_sleep(1);
      }
      __syncthreads();   // also orders the LDS fill before first ds_read

      // issue h2_{t-1} loads; ih MFMAs (a1 + LDS weights) run underneath
      i4v a2[16];
      load16_nw(hbuf + (size_t)(2 + (t & 1)) * kPlane + cons_off, a2);

      const f4v z4 = {0.f, 0.f, 0.f, 0.f};
      f4v acc0 = z4, acc1 = z4, acc2 = z4, acc2x = z4;
#pragma unroll
      for (int kt = 0; kt < 16; ++kt) {
        const s8v b0 = *(const s8v*)&ldsw[(size_t)((0 + u) * 16 + kt) * 512 + lane * 8];
        const s8v b1 = *(const s8v*)&ldsw[(size_t)((2 + u) * 16 + kt) * 512 + lane * 8];
        const s8v b2 = *(const s8v*)&ldsw[(size_t)((4 + u) * 16 + kt) * 512 + lane * 8];
        acc0  = MFMA16(a1[kt], b0, acc0, 0, 0, 0);
        acc1  = MFMA16(a1[kt], b1, acc1, 0, 0, 0);
        acc2x = MFMA16(a1[kt], b2, acc2x, 0, 0, 0);
      }
      asm volatile("s_waitcnt vmcnt(0)" ::: "memory");
      __builtin_amdgcn_sched_barrier(0);   // rule #18: pin hh MFMAs below
#pragma unroll
      for (int kt = 0; kt < 16; ++kt) {
        const s8v av = __builtin_bit_cast(s8v, a2[kt]);
        acc0 = MFMA16(av, bh[0][kt], acc0, 0, 0, 0);
        acc1 = MFMA16(av, bh[1][kt], acc1, 0, 0, 0);
        acc2 = MFMA16(av, bh[2][kt], acc2, 0, 0, 0);
      }

      unsigned hv[4];
#pragma unroll
      for (int r = 0; r < 4; ++r) {
        float rr = fsig(acc0[r] + br);
        float zz = fsig(acc1[r] + bz);
        float nn = ftanh(acc2x[r] + bni + rr * (acc2[r] + bnh));
        float hn = (1.f - zz) * nn + zz * hp[r];
        hp[r] = hn;
        hv[r] = f2bf(hn);
      }

      u16* pb = hbuf + (size_t)(2 + ((t + 1) & 1)) * kPlane + prod_off;
      store_h_l1(pb + (size_t)(mrow + 0) * 8, pb + (size_t)(mrow + 1) * 8,
                 pb + (size_t)(mrow + 2) * 8, pb + (size_t)(mrow + 3) * 8,
                 hv[0], hv[1], hv[2], hv[3]);
      __syncthreads();
      if (tid == 0)
        __hip_atomic_fetch_add(mybar, 1u, __ATOMIC_RELAXED,
                               __HIP_MEMORY_SCOPE_AGENT);
      if (t + 1 < TC) {   // h1 frags for t+1 fly during next wait phase
        const u16* hb = h1base + (size_t)(t + 1) * kPlane;
#pragma unroll
        for (int kt = 0; kt < 16; ++kt)
          a1[kt] = *(const s8v*)(hb + (size_t)kt * 512);
      }
    }
#pragma unroll
    for (int r = 0; r < 4; ++r)
      mycarry[(size_t)(bbase + r) * 512 + jg] = hp[r];
  }
}

// ---------------------------------------------------------------------------
__global__ __launch_bounds__(128)
void fc_kernel(const float* __restrict__ h, const float* __restrict__ wfc,
               const float* __restrict__ bfc, float* __restrict__ out) {
  const int b = blockIdx.x;
  const int n = threadIdx.x;
  const float* hrow = h + (size_t)b * kH;
  const float* wrow = wfc + (size_t)n * kH;
  float acc = 0.f;
#pragma unroll 4
  for (int k = 0; k < kH; k += 4) {
    const float4 hv = *(const float4*)&hrow[k];
    const float4 wv = *(const float4*)&wrow[k];
    acc = fmaf(hv.x, wv.x, acc); acc = fmaf(hv.y, wv.y, acc);
    acc = fmaf(hv.z, wv.z, acc); acc = fmaf(hv.w, wv.w, acc);
  }
  out[(size_t)b * kNOUT + n] = acc + bfc[n];
}

// ---------------------------------------------------------------------------
extern "C" void kernel_launch(void* const* d_in, const int* in_sizes, int n_in,
                              void* d_out, int out_size, void* d_ws, size_t ws_size,
                              hipStream_t stream) {
  const float* x     = (const float*)d_in[0];
  const float* w_ih0 = (const float*)d_in[1];
  const float* w_hh0 = (const float*)d_in[2];
  const float* b_ih0 = (const float*)d_in[3];
  const float* b_hh0 = (const float*)d_in[4];
  const float* w_ih1 = (const float*)d_in[5];
  const float* w_hh1 = (const float*)d_in[6];
  const float* b_ih1 = (const float*)d_in[7];
  const float* b_hh1 = (const float*)d_in[8];
  const float* w_fc  = (const float*)d_in[9];
  const float* b_fc  = (const float*)d_in[10];
  float* out = (float*)d_out;

  // workspace: slabs 4.7 MB + xpl 16.8 MB + h1pl 2*TC*256KB + hbuf 1 MB +
  // carry 1 MB + bar.  TC=64 -> ~57 MB total.
  auto need = [](int tc) -> size_t {
    size_t s = 0;
    s += 3 * (size_t)kG3 * kH * 2;        // slab0hh, slab1hh, slab1ih
    s += (size_t)kG3 * kDIN * 2;          // slab0ih
    s += (size_t)kT * kXStep * 2;         // xpl
    s += 2 * (size_t)tc * kPlane * 2;     // h1pl (chunk-parity dbuf)
    s += 4 * (size_t)kPlane * 2;          // hbuf
    s += 2 * (size_t)kB * kH * 4;         // carry
    s += 65536;
    return s;
  };
  int TC = 64;
  while (TC > 2 && need(TC) > ws_size) TC >>= 1;
  const int nc = kT / TC;

  char* p = (char*)d_ws;
  auto carve = [&](size_t bytes) {
    char* r = p; p += (bytes + 255) & ~(size_t)255; return r;
  };
  u16* slab0hh = (u16*)carve((size_t)kG3 * kH * 2);
  u16* slab1hh = (u16*)carve((size_t)kG3 * kH * 2);
  u16* slab1ih = (u16*)carve((size_t)kG3 * kH * 2);
  u16* slab0ih = (u16*)carve((size_t)kG3 * kDIN * 2);
  u16* xpl     = (u16*)carve((size_t)kT * kXStep * 2);
  u16* h1pl    = (u16*)carve(2 * (size_t)TC * kPlane * 2);
  u16* hbuf    = (u16*)carve(4 * (size_t)kPlane * 2);
  float* carry = (float*)carve(2 * (size_t)kB * kH * 4);
  unsigned* bar = (unsigned*)carve(32 * 64 * sizeof(unsigned));

  // prologue: swizzles + zero h planes/carries + barrier counters
  build_wslab<<<384, 256, 0, stream>>>(w_hh0, slab0hh);
  build_wslab<<<384, 256, 0, stream>>>(w_hh1, slab1hh);
  build_wslab<<<384, 256, 0, stream>>>(w_ih1, slab1ih);
  build_wslab_ih0<<<48, 256, 0, stream>>>(w_ih0, slab0ih);
  build_xplane<<<4096, 256, 0, stream>>>(x, xpl);
  hipMemsetAsync(hbuf, 0, 4 * (size_t)kPlane * 2 + 2 * (size_t)kB * kH * 4, stream);
  hipMemsetAsync(bar, 0, 32 * 64 * sizeof(unsigned), stream);

  // pipeline: dispatch c runs rec0(c) + rec1(c-1); no serial GEMMs.
  for (int c = 0; c <= nc; ++c) {
    unsigned base16 = (unsigned)c * 16u * (unsigned)TC;
    rec_fused<<<dim3(256), dim3(256), 0, stream>>>(
        c, TC, nc, base16, bar, xpl,
        slab0hh, slab0ih, slab1hh, slab1ih,
        b_ih0, b_hh0, b_ih1, b_hh1,
        h1pl, hbuf, carry);
  }

  // final FC on layer-1 terminal state
  fc_kernel<<<dim3(kB), dim3(kNOUT), 0, stream>>>(
      carry + (size_t)kB * kH, w_fc, b_fc, out);
}